// Round 2
// baseline (697.484 us; speedup 1.0000x reference)
//
#include <hip/hip_runtime.h>
#include <hip/hip_bf16.h>
#include <math.h>

#define GG 2
#define NPG 332
#define NN 664
#define EE 21248
#define EPG 10624          // edges per graph
#define KHD 6
#define KP1 166
#define KP2 83
#define DIM 332
#define DD3 128
#define MAXIN 128
#define KTOT 2324          // 7*332
#define W2ROWS 1992        // 6*332

// ---------------- A-build for conv1: h from W1 rows (pos is one-hot), zero xt & cnt ----------------
__global__ void k_afull1(const float* __restrict__ X, const float* __restrict__ W1,
                         float* __restrict__ A, float* __restrict__ xt, int* __restrict__ cnt) {
    int n = blockIdx.x;          // 0..663
    int t = threadIdx.x;         // 256
    __shared__ float hh[8];
    if (t < 6) hh[t] = fmaxf(W1[(n % DIM) * KHD + t], 0.f);
    if (t == 6) hh[6] = 1.f;
    if (t == 0) cnt[n] = 0;
    for (int o = t; o < DIM; o += 256) xt[(size_t)n * DIM + o] = 0.f;
    __syncthreads();
    const float* xr = X + (size_t)n * DIM;
    float* ar = A + (size_t)n * KTOT;
    for (int idx = t; idx < KTOT; idx += 256) {
        int k = idx / DIM;       // constant divisor -> magic mul
        int i = idx - k * DIM;
        ar[idx] = hh[k] * xr[i];
    }
}

// ---------------- A-build for conv2: h via perm1 row of W1_2, zero xt ----------------
__global__ void k_afull2(const float* __restrict__ Xp, const float* __restrict__ W1,
                         const int* __restrict__ perm, float* __restrict__ A, float* __restrict__ xt) {
    int n = blockIdx.x;          // 0..331
    int t = threadIdx.x;
    __shared__ float hh[8];
    if (t < 6) { int p = perm[n] % DIM; hh[t] = fmaxf(W1[p * KHD + t], 0.f); }
    if (t == 6) hh[6] = 1.f;
    for (int o = t; o < DIM; o += 256) xt[(size_t)n * DIM + o] = 0.f;
    __syncthreads();
    const float* xr = Xp + (size_t)n * DIM;
    float* ar = A + (size_t)n * KTOT;
    for (int idx = t; idx < KTOT; idx += 256) {
        int k = idx / DIM;
        int i = idx - k * DIM;
        ar[idx] = hh[k] * xr[i];
    }
}

// ---------------- adjacency bucket build (conv1 only; conv2's is fused in k_pool) ----------------
__global__ void k_bucket(const int* __restrict__ dst, int* cnt, int* bucket) {
    int e = blockIdx.x * 256 + threadIdx.x;
    if (e >= EE) return;
    int d = dst[e];
    int slot = atomicAdd(&cnt[d], 1);
    if (slot < MAXIN) bucket[d * MAXIN + slot] = e;
}

// ---------------- GEMM: xt[M][332] += A[M][2324] @ B[2324][332], split-K over z ----------------
// B row r: r<1992 ? W2 + r*332 : nb + (r-1992)*332
#define BM 64
#define BN 64
#define BK 16
#define SPLITK 8

__global__ __launch_bounds__(256) void k_gemm(const float* __restrict__ A,
                                              const float* __restrict__ W2,
                                              const float* __restrict__ nb,
                                              float* __restrict__ C, int M) {
    __shared__ float As[BK][BM + 4];   // stride 68 floats: 16B-aligned rows, conflict-free
    __shared__ float Bs[BK][BN];
    int tid = threadIdx.x;
    int tx = tid & 15, ty = tid >> 4;
    int col0 = blockIdx.x * BN, row0 = blockIdx.y * BM;
    const int kc = (KTOT + SPLITK - 1) / SPLITK;    // 291
    int k0 = blockIdx.z * kc;
    int k1 = k0 + kc; if (k1 > KTOT) k1 = KTOT;
    float acc[4][4] = {};
    for (int kb = k0; kb < k1; kb += BK) {
        {   // stage A: As[kk][m] = A[row0+m][kb+kk]
            int m0 = tid >> 4;      // 0..15
            int kk = tid & 15;
            int kg = kb + kk;
            bool kok = kg < k1;
#pragma unroll
            for (int mi = 0; mi < 4; ++mi) {
                int mm = m0 + mi * 16;
                int r = row0 + mm;
                As[kk][mm] = (kok && r < M) ? A[(size_t)r * KTOT + kg] : 0.f;
            }
        }
        {   // stage B: Bs[kk][n] = B[kb+kk][col0+n]
            int n = tid & 63;
            int kb4 = tid >> 6;     // 0..3
            int c = col0 + n;
#pragma unroll
            for (int ki = 0; ki < 4; ++ki) {
                int kk = kb4 + ki * 4;
                int r = kb + kk;
                float v = 0.f;
                if (r < k1 && c < DIM) {
                    const float* Brow = (r < W2ROWS) ? (W2 + (size_t)r * DIM)
                                                     : (nb + (size_t)(r - W2ROWS) * DIM);
                    v = Brow[c];
                }
                Bs[kk][n] = v;
            }
        }
        __syncthreads();
#pragma unroll
        for (int kk = 0; kk < BK; ++kk) {
            float a[4], b[4];
#pragma unroll
            for (int i = 0; i < 4; ++i) a[i] = As[kk][ty * 4 + i];
#pragma unroll
            for (int j = 0; j < 4; ++j) b[j] = Bs[kk][tx * 4 + j];
#pragma unroll
            for (int i = 0; i < 4; ++i)
#pragma unroll
                for (int j = 0; j < 4; ++j) acc[i][j] += a[i] * b[j];
        }
        __syncthreads();
    }
#pragma unroll
    for (int i = 0; i < 4; ++i) {
        int r = row0 + ty * 4 + i;
        if (r < M) {
#pragma unroll
            for (int j = 0; j < 4; ++j) {
                int c = col0 + tx * 4 + j;
                if (c < DIM) atomicAdd(&C[(size_t)r * DIM + c], acc[i][j]);
            }
        }
    }
}

// ---------------- softmax-weighted aggregation + bias ----------------
__global__ void k_agg(const float* __restrict__ xt, const int* __restrict__ cnt,
                      const int* __restrict__ bucket, const int* __restrict__ srcArr,
                      const float* __restrict__ eattr, const int* __restrict__ newidx,
                      const float* __restrict__ bias, float* __restrict__ out) {
    __shared__ float alpha[MAXIN];
    __shared__ int sidx[MAXIN];
    __shared__ float red[256];
    int n = blockIdx.x, t = threadIdx.x;
    int c = cnt[n]; if (c > MAXIN) c = MAXIN;
    float mysum = 0.f;
    for (int j = t; j < c; j += 256) {
        int e = bucket[n * MAXIN + j];
        int s = srcArr[e];
        if (newidx) s = newidx[s];
        float ex = expf(eattr[e]);
        alpha[j] = ex;
        sidx[j] = s;
        mysum += ex;
    }
    red[t] = mysum;
    __syncthreads();
    for (int off = 128; off > 0; off >>= 1) {
        if (t < off) red[t] += red[t + off];
        __syncthreads();
    }
    const float eself = 2.718281828459045f;
    float inv = 1.f / (red[0] + eself);
    __syncthreads();
    for (int j = t; j < c; j += 256) alpha[j] *= inv;
    __syncthreads();
    float aself = eself * inv;
    for (int o = t; o < DIM; o += 256) {
        float acc = bias[o] + aself * xt[(size_t)n * DIM + o];
        for (int j = 0; j < c; ++j) acc += alpha[j] * xt[(size_t)sidx[j] * DIM + o];
        out[(size_t)n * DIM + o] = acc;
    }
}

// ---------------- fused pool: score + topk + xnew + readout (+ next-level bucket build) ----------------
__global__ void k_pool(const float* __restrict__ xv, const float* __restrict__ w,
                       int n_per, int k,
                       int* __restrict__ perm, int* __restrict__ newidx,
                       float* __restrict__ xnew, float* __restrict__ z, int zbase,
                       const int* __restrict__ src, const int* __restrict__ dst,
                       int* __restrict__ cnt2, int* __restrict__ bucket2) {
    __shared__ float s[NPG];
    __shared__ short permS[NPG];
    __shared__ short nidxS[NPG];
    int g = blockIdx.x, t = threadIdx.x;   // 256 threads, 2 blocks
    float wn = 0.f;
    for (int j = 0; j < DIM; ++j) { float wv = w[j]; wn += wv * wv; }
    float nw = sqrtf(wn);
    for (int i = t; i < n_per; i += 256) {
        const float* xr = xv + (size_t)(g * n_per + i) * DIM;
        float d = 0.f;
        for (int j = 0; j < DIM; ++j) d += xr[j] * w[j];
        s[i] = 1.f / (1.f + expf(-d / nw));
    }
    __syncthreads();
    for (int i = t; i < n_per; i += 256) {
        float si = s[i];
        int r = 0;
        for (int j = 0; j < n_per; ++j) {
            float sj = s[j];
            r += (sj > si) || (sj == si && j < i);
        }
        int node = g * n_per + i;
        if (r < k) {
            permS[r] = (short)i;
            nidxS[i] = (short)(g * k + r);
            perm[g * k + r] = node;
            newidx[node] = g * k + r;
        } else {
            nidxS[i] = -1;
            newidx[node] = -1;
        }
    }
    __syncthreads();
    for (int idx = t; idx < k * DIM; idx += 256) {
        int r = idx / DIM, o = idx - r * DIM;
        int li = permS[r];
        xnew[(size_t)(g * k + r) * DIM + o] = xv[(size_t)(g * n_per + li) * DIM + o] * s[li];
    }
    for (int o = t; o < DIM; o += 256) {
        float mx = -3.4e38f, sm = 0.f;
        for (int r = 0; r < k; ++r) {
            int li = permS[r];
            float v = xv[(size_t)(g * n_per + li) * DIM + o] * s[li];
            mx = fmaxf(mx, v);
            sm += v;
        }
        z[(size_t)g * 1328 + zbase + o] = mx;
        z[(size_t)g * 1328 + zbase + DIM + o] = sm / (float)k;
    }
    if (cnt2) {
        for (int i = t; i < k; i += 256) cnt2[g * k + i] = 0;
        __syncthreads();
        int e0 = g * EPG;
        for (int e = e0 + t; e < e0 + EPG; e += 256) {
            int ns = nidxS[src[e] - g * n_per];
            int nd = nidxS[dst[e] - g * n_per];
            if (ns >= 0 && nd >= 0) {
                int slot = atomicAdd(&cnt2[nd], 1);
                if (slot < MAXIN) bucket2[nd * MAXIN + slot] = e;
            }
        }
    }
}

// ---------------- fused head: fc1+bn+relu, fc2+bn+relu, fc3 ----------------
__global__ void k_head(const float* __restrict__ z,
                       const float* __restrict__ fc1W, const float* __restrict__ fc1b,
                       const float* __restrict__ bn1g, const float* __restrict__ bn1b,
                       const float* __restrict__ fc2W, const float* __restrict__ fc2b,
                       const float* __restrict__ bn2g, const float* __restrict__ bn2b,
                       const float* __restrict__ fc3W, const float* __restrict__ fc3b,
                       float* __restrict__ out) {
    __shared__ float z1[2][DIM];
    __shared__ float z2[2][DD3];
    int t = threadIdx.x;
    for (int j = t; j < DIM; j += 256) {
        float a0 = fc1b[j], a1 = a0;
        for (int i = 0; i < 1328; ++i) {
            float wv = fc1W[(size_t)i * DIM + j];
            a0 += z[i] * wv;
            a1 += z[1328 + i] * wv;
        }
        float m = 0.5f * (a0 + a1);
        float d0 = a0 - m, d1 = a1 - m;
        float v = 0.5f * (d0 * d0 + d1 * d1);
        float is = 1.f / sqrtf(v + 1e-5f);
        float gj = bn1g[j], bj = bn1b[j];
        z1[0][j] = fmaxf(d0 * is * gj + bj, 0.f);
        z1[1][j] = fmaxf(d1 * is * gj + bj, 0.f);
    }
    __syncthreads();
    for (int j = t; j < DD3; j += 256) {
        float a0 = fc2b[j], a1 = a0;
        for (int i = 0; i < DIM; ++i) {
            float wv = fc2W[(size_t)i * DD3 + j];
            a0 += z1[0][i] * wv;
            a1 += z1[1][i] * wv;
        }
        float m = 0.5f * (a0 + a1);
        float d0 = a0 - m, d1 = a1 - m;
        float v = 0.5f * (d0 * d0 + d1 * d1);
        float is = 1.f / sqrtf(v + 1e-5f);
        float gj = bn2g[j], bj = bn2b[j];
        z2[0][j] = fmaxf(d0 * is * gj + bj, 0.f);
        z2[1][j] = fmaxf(d1 * is * gj + bj, 0.f);
    }
    __syncthreads();
    if (t < 4) {
        int g = t >> 1, c = t & 1;
        float acc = fc3b[c];
        for (int i = 0; i < DD3; ++i) acc += z2[g][i] * fc3W[i * 2 + c];
        out[g * 2 + c] = acc;
    }
}

extern "C" void kernel_launch(void* const* d_in, const int* in_sizes, int n_in,
                              void* d_out, int out_size, void* d_ws, size_t ws_size,
                              hipStream_t stream) {
    (void)in_sizes; (void)n_in; (void)out_size; (void)ws_size;
    const float* x     = (const float*)d_in[0];
    const int*   eidx  = (const int*)d_in[1];
    const float* eattr = (const float*)d_in[3];
    const float* c1W1  = (const float*)d_in[6];
    const float* c1W2  = (const float*)d_in[7];
    const float* c1nb  = (const float*)d_in[8];
    const float* c1b   = (const float*)d_in[9];
    const float* p1w   = (const float*)d_in[10];
    const float* c2W1  = (const float*)d_in[11];
    const float* c2W2  = (const float*)d_in[12];
    const float* c2nb  = (const float*)d_in[13];
    const float* c2b   = (const float*)d_in[14];
    const float* p2w   = (const float*)d_in[15];
    const float* fc1W  = (const float*)d_in[16];
    const float* fc1b  = (const float*)d_in[17];
    const float* bn1g  = (const float*)d_in[18];
    const float* bn1b  = (const float*)d_in[19];
    const float* fc2W  = (const float*)d_in[20];
    const float* fc2b  = (const float*)d_in[21];
    const float* bn2g  = (const float*)d_in[22];
    const float* bn2b  = (const float*)d_in[23];
    const float* fc3W  = (const float*)d_in[24];
    const float* fc3b  = (const float*)d_in[25];

    const int* src = eidx;
    const int* dst = eidx + EE;

    char* w = (char*)d_ws;
    auto alloc = [&](size_t bytes) { void* p = (void*)w; w += ((bytes + 255) / 256) * 256; return p; };
    float* Abuf    = (float*)alloc((size_t)NN * KTOT * 4);   // shared by conv1 & conv2
    int*   cnt1    = (int*)alloc(NN * 4);
    int*   bucket1 = (int*)alloc((size_t)NN * MAXIN * 4);
    float* xt1     = (float*)alloc((size_t)NN * DIM * 4);
    float* out1    = (float*)alloc((size_t)NN * DIM * 4);
    int*   perm1   = (int*)alloc(GG * KP1 * 4);
    int*   newidx1 = (int*)alloc(NN * 4);
    float* x1p     = (float*)alloc((size_t)GG * KP1 * DIM * 4);
    float* zbuf    = (float*)alloc(GG * 1328 * 4);
    int*   cnt2    = (int*)alloc(GG * KP1 * 4);
    int*   bucket2 = (int*)alloc((size_t)GG * KP1 * MAXIN * 4);
    float* xt2     = (float*)alloc((size_t)GG * KP1 * DIM * 4);
    float* out2    = (float*)alloc((size_t)GG * KP1 * DIM * 4);
    int*   perm2   = (int*)alloc(GG * KP2 * 4);
    int*   newidx2 = (int*)alloc(GG * KP1 * 4);
    float* x2p     = (float*)alloc((size_t)GG * KP2 * DIM * 4);

    // ---- conv1 ----
    k_afull1<<<NN, 256, 0, stream>>>(x, c1W1, Abuf, xt1, cnt1);
    k_bucket<<<(EE + 255) / 256, 256, 0, stream>>>(dst, cnt1, bucket1);
    k_gemm<<<dim3((DIM + BN - 1) / BN, (NN + BM - 1) / BM, SPLITK), 256, 0, stream>>>(
        Abuf, c1W2, c1nb, xt1, NN);
    k_agg<<<NN, 256, 0, stream>>>(xt1, cnt1, bucket1, src, eattr, nullptr, c1b, out1);

    // ---- pool1 (+ readout1 + bucket2 build) ----
    k_pool<<<GG, 256, 0, stream>>>(out1, p1w, NPG, KP1, perm1, newidx1, x1p, zbuf, 0,
                                   src, dst, cnt2, bucket2);

    // ---- conv2 ----
    k_afull2<<<GG * KP1, 256, 0, stream>>>(x1p, c2W1, perm1, Abuf, xt2);
    k_gemm<<<dim3((DIM + BN - 1) / BN, (GG * KP1 + BM - 1) / BM, SPLITK), 256, 0, stream>>>(
        Abuf, c2W2, c2nb, xt2, GG * KP1);
    k_agg<<<GG * KP1, 256, 0, stream>>>(xt2, cnt2, bucket2, src, eattr, newidx1, c2b, out2);

    // ---- pool2 (+ readout2) ----
    k_pool<<<GG, 256, 0, stream>>>(out2, p2w, KP1, KP2, perm2, newidx2, x2p, zbuf, 664,
                                   nullptr, nullptr, nullptr, nullptr);

    // ---- head ----
    k_head<<<1, 256, 0, stream>>>(zbuf, fc1W, fc1b, bn1g, bn1b,
                                  fc2W, fc2b, bn2g, bn2b, fc3W, fc3b, (float*)d_out);
}

// Round 3
// 416.829 us; speedup vs baseline: 1.6733x; 1.6733x over previous
//
#include <hip/hip_runtime.h>
#include <hip/hip_bf16.h>
#include <math.h>

#define GG 2
#define NPG 332
#define NN 664
#define EE 21248
#define KHD 6
#define KP1 166
#define KP2 83
#define DIM 332
#define DD3 128
#define MAXIN 128
#define KTOT 2324          // 7*332
#define W2ROWS 1992        // 6*332

// ---------------- A-build conv1: h from W1 rows (pos one-hot), zero xt & cnt ----------------
__global__ void k_afull1(const float* __restrict__ X, const float* __restrict__ W1,
                         float* __restrict__ A, float* __restrict__ xt, int* __restrict__ cnt) {
    int n = blockIdx.x;          // 0..663
    int t = threadIdx.x;         // 256
    __shared__ float hh[8];
    if (t < 6) hh[t] = fmaxf(W1[(n % DIM) * KHD + t], 0.f);
    if (t == 6) hh[6] = 1.f;
    if (t == 0) cnt[n] = 0;
    for (int o = t; o < DIM; o += 256) xt[(size_t)n * DIM + o] = 0.f;
    __syncthreads();
    const float* xr = X + (size_t)n * DIM;
    float* ar = A + (size_t)n * KTOT;
    for (int idx = t; idx < KTOT; idx += 256) {
        int k = idx / DIM;
        int i = idx - k * DIM;
        ar[idx] = hh[k] * xr[i];
    }
}

// ---------------- A-build conv2: h via perm row of W1, zero xt ----------------
__global__ void k_afull2(const float* __restrict__ Xp, const float* __restrict__ W1,
                         const int* __restrict__ perm, float* __restrict__ A, float* __restrict__ xt) {
    int n = blockIdx.x;          // 0..331
    int t = threadIdx.x;
    __shared__ float hh[8];
    if (t < 6) { int p = perm[n] % DIM; hh[t] = fmaxf(W1[p * KHD + t], 0.f); }
    if (t == 6) hh[6] = 1.f;
    for (int o = t; o < DIM; o += 256) xt[(size_t)n * DIM + o] = 0.f;
    __syncthreads();
    const float* xr = Xp + (size_t)n * DIM;
    float* ar = A + (size_t)n * KTOT;
    for (int idx = t; idx < KTOT; idx += 256) {
        int k = idx / DIM;
        int i = idx - k * DIM;
        ar[idx] = hh[k] * xr[i];
    }
}

// ---------------- bucket build, conv1 (no remap) ----------------
__global__ void k_bucket(const int* __restrict__ dst, int* cnt, int* bucket) {
    int e = blockIdx.x * 256 + threadIdx.x;
    if (e >= EE) return;
    int d = dst[e];
    int slot = atomicAdd(&cnt[d], 1);
    if (slot < MAXIN) bucket[d * MAXIN + slot] = e;
}

// ---------------- bucket build, conv2 (remap through newidx) ----------------
__global__ void k_bucketB(const int* __restrict__ src, const int* __restrict__ dst,
                          const int* __restrict__ newidx, int* cnt, int* bucket) {
    int e = blockIdx.x * 256 + threadIdx.x;
    if (e >= EE) return;
    int ns = newidx[src[e]];
    int nd = newidx[dst[e]];
    if (ns < 0 || nd < 0) return;
    int slot = atomicAdd(&cnt[nd], 1);
    if (slot < MAXIN) bucket[nd * MAXIN + slot] = e;
}

// ---------------- GEMM: C[M][332] += A[M][2324] @ B[2324][332], split-K ----------------
#define BM 64
#define BN 64
#define BK 16
#define SPLITK 8

__global__ __launch_bounds__(256) void k_gemm(const float* __restrict__ A,
                                              const float* __restrict__ W2,
                                              const float* __restrict__ nb,
                                              float* __restrict__ C, int M) {
    __shared__ float As[BK][BM + 4];
    __shared__ float Bs[BK][BN];
    int tid = threadIdx.x;
    int tx = tid & 15, ty = tid >> 4;
    int col0 = blockIdx.x * BN, row0 = blockIdx.y * BM;
    const int kc = (KTOT + SPLITK - 1) / SPLITK;    // 291
    int k0 = blockIdx.z * kc;
    int k1 = k0 + kc; if (k1 > KTOT) k1 = KTOT;
    float acc[4][4] = {};
    for (int kb = k0; kb < k1; kb += BK) {
        {
            int m0 = tid >> 4;
            int kk = tid & 15;
            int kg = kb + kk;
            bool kok = kg < k1;
#pragma unroll
            for (int mi = 0; mi < 4; ++mi) {
                int mm = m0 + mi * 16;
                int r = row0 + mm;
                As[kk][mm] = (kok && r < M) ? A[(size_t)r * KTOT + kg] : 0.f;
            }
        }
        {
            int n = tid & 63;
            int kb4 = tid >> 6;
            int c = col0 + n;
#pragma unroll
            for (int ki = 0; ki < 4; ++ki) {
                int kk = kb4 + ki * 4;
                int r = kb + kk;
                float v = 0.f;
                if (r < k1 && c < DIM) {
                    const float* Brow = (r < W2ROWS) ? (W2 + (size_t)r * DIM)
                                                     : (nb + (size_t)(r - W2ROWS) * DIM);
                    v = Brow[c];
                }
                Bs[kk][n] = v;
            }
        }
        __syncthreads();
#pragma unroll
        for (int kk = 0; kk < BK; ++kk) {
            float a[4], b[4];
#pragma unroll
            for (int i = 0; i < 4; ++i) a[i] = As[kk][ty * 4 + i];
#pragma unroll
            for (int j = 0; j < 4; ++j) b[j] = Bs[kk][tx * 4 + j];
#pragma unroll
            for (int i = 0; i < 4; ++i)
#pragma unroll
                for (int j = 0; j < 4; ++j) acc[i][j] += a[i] * b[j];
        }
        __syncthreads();
    }
#pragma unroll
    for (int i = 0; i < 4; ++i) {
        int r = row0 + ty * 4 + i;
        if (r < M) {
#pragma unroll
            for (int j = 0; j < 4; ++j) {
                int c = col0 + tx * 4 + j;
                if (c < DIM) atomicAdd(&C[(size_t)r * DIM + c], acc[i][j]);
            }
        }
    }
}

// ---------------- softmax-weighted aggregation + bias ----------------
__global__ void k_agg(const float* __restrict__ xt, const int* __restrict__ cnt,
                      const int* __restrict__ bucket, const int* __restrict__ srcArr,
                      const float* __restrict__ eattr, const int* __restrict__ newidx,
                      const float* __restrict__ bias, float* __restrict__ out) {
    __shared__ float alpha[MAXIN];
    __shared__ int sidx[MAXIN];
    __shared__ float red[256];
    int n = blockIdx.x, t = threadIdx.x;
    int c = cnt[n]; if (c > MAXIN) c = MAXIN;
    float mysum = 0.f;
    for (int j = t; j < c; j += 256) {
        int e = bucket[n * MAXIN + j];
        int s = srcArr[e];
        if (newidx) s = newidx[s];
        float ex = expf(eattr[e]);
        alpha[j] = ex;
        sidx[j] = s;
        mysum += ex;
    }
    red[t] = mysum;
    __syncthreads();
    for (int off = 128; off > 0; off >>= 1) {
        if (t < off) red[t] += red[t + off];
        __syncthreads();
    }
    const float eself = 2.718281828459045f;
    float inv = 1.f / (red[0] + eself);
    __syncthreads();
    for (int j = t; j < c; j += 256) alpha[j] *= inv;
    __syncthreads();
    float aself = eself * inv;
    for (int o = t; o < DIM; o += 256) {
        float acc = bias[o] + aself * xt[(size_t)n * DIM + o];
        for (int j = 0; j < c; ++j) acc += alpha[j] * xt[(size_t)sidx[j] * DIM + o];
        out[(size_t)n * DIM + o] = acc;
    }
}

// ---------------- score[n] = sigmoid(dot(xv[n],w)/||w||), one block per node ----------------
__global__ void k_score(const float* __restrict__ xv, const float* __restrict__ w,
                        float* __restrict__ score) {
    int n = blockIdx.x, t = threadIdx.x;     // 64 threads
    float a = 0.f, b = 0.f;
    for (int j = t; j < DIM; j += 64) {
        float wv = w[j];
        a += xv[(size_t)n * DIM + j] * wv;
        b += wv * wv;
    }
    for (int off = 32; off > 0; off >>= 1) {
        a += __shfl_down(a, off);
        b += __shfl_down(b, off);
    }
    if (t == 0) score[n] = 1.f / (1.f + expf(-a / sqrtf(b)));
}

// ---------------- stable top-k rank per graph; also zeroes next-stage accumulators ----------------
__global__ void k_topk(const float* __restrict__ score, int n_per, int k,
                       int* __restrict__ perm, int* __restrict__ newidx,
                       int* __restrict__ czero, int cn,
                       float* __restrict__ fzero1, int fn1,
                       float* __restrict__ fzero2, int fn2) {
    __shared__ float s[NPG];
    int g = blockIdx.x, t = threadIdx.x;     // 384 threads
    for (int i = t; i < n_per; i += 384) s[i] = score[g * n_per + i];
    if (czero) for (int i = g * 384 + t; i < cn; i += GG * 384) czero[i] = 0;
    if (fzero1) for (int i = g * 384 + t; i < fn1; i += GG * 384) fzero1[i] = 0.f;
    if (fzero2) for (int i = g * 384 + t; i < fn2; i += GG * 384) fzero2[i] = 0.f;
    __syncthreads();
    for (int i = t; i < n_per; i += 384) {
        float si = s[i];
        int r = 0;
        for (int j = 0; j < n_per; ++j) {
            float sj = s[j];
            r += (sj > si) || (sj == si && j < i);
        }
        int node = g * n_per + i;
        if (r < k) {
            perm[g * k + r] = node;
            newidx[node] = g * k + r;
        } else {
            newidx[node] = -1;
        }
    }
}

// ---------------- gather: xnew (optional) + readout max/mean, column-parallel ----------------
__global__ void k_gather(const float* __restrict__ xv, const float* __restrict__ score,
                         const int* __restrict__ perm, int k,
                         float* __restrict__ xnew, float* __restrict__ z, int zbase) {
    int g = blockIdx.y;
    int o = blockIdx.x * 256 + threadIdx.x;
    if (o >= DIM) return;
    float mx = -3.4e38f, sm = 0.f;
    for (int r = 0; r < k; ++r) {
        int p = perm[g * k + r];
        float v = xv[(size_t)p * DIM + o] * score[p];
        if (xnew) xnew[(size_t)(g * k + r) * DIM + o] = v;
        mx = fmaxf(mx, v);
        sm += v;
    }
    z[(size_t)g * 1328 + zbase + o] = mx;
    z[(size_t)g * 1328 + zbase + DIM + o] = sm / (float)k;
}

// ---------------- fc1 partials: hacc[2][332] += z[2][1328-chunk] @ W-chunk ----------------
__global__ void k_fc1(const float* __restrict__ z, const float* __restrict__ W,
                      float* __restrict__ hacc) {
    __shared__ float zs[2][166];
    int t = threadIdx.x;                 // 128
    int j = blockIdx.x * 128 + t;
    int i0 = blockIdx.y * 166;
    for (int i = t; i < 166; i += 128) {
        zs[0][i] = z[i0 + i];
        zs[1][i] = z[1328 + i0 + i];
    }
    __syncthreads();
    if (j >= DIM) return;
    float a0 = 0.f, a1 = 0.f;
    for (int i = 0; i < 166; ++i) {
        float wv = W[(size_t)(i0 + i) * DIM + j];
        a0 += zs[0][i] * wv;
        a1 += zs[1][i] * wv;
    }
    atomicAdd(&hacc[j], a0);
    atomicAdd(&hacc[DIM + j], a1);
}

// ---------------- fc2 partials: per-chunk BN1+relu then f2acc += z1chunk @ Wchunk ----------------
__global__ void k_fc2(const float* __restrict__ hacc, const float* __restrict__ fc1b,
                      const float* __restrict__ bn1g, const float* __restrict__ bn1b,
                      const float* __restrict__ W, float* __restrict__ f2acc) {
    __shared__ float z1s[2][83];
    int t = threadIdx.x;                 // 128
    int i0 = blockIdx.x * 83;
    if (t < 83) {
        int col = i0 + t;
        float a0 = hacc[col] + fc1b[col];
        float a1 = hacc[DIM + col] + fc1b[col];
        float m = 0.5f * (a0 + a1);
        float d0 = a0 - m, d1 = a1 - m;
        float v = 0.5f * (d0 * d0 + d1 * d1);
        float is = 1.f / sqrtf(v + 1e-5f);
        float gj = bn1g[col], bj = bn1b[col];
        z1s[0][t] = fmaxf(d0 * is * gj + bj, 0.f);
        z1s[1][t] = fmaxf(d1 * is * gj + bj, 0.f);
    }
    __syncthreads();
    float a0 = 0.f, a1 = 0.f;
    for (int i = 0; i < 83; ++i) {
        float wv = W[(size_t)(i0 + i) * DD3 + t];
        a0 += z1s[0][i] * wv;
        a1 += z1s[1][i] * wv;
    }
    atomicAdd(&f2acc[t], a0);
    atomicAdd(&f2acc[DD3 + t], a1);
}

// ---------------- final: BN2+relu+fc3 ----------------
__global__ void k_head3(const float* __restrict__ f2acc, const float* __restrict__ fc2b,
                        const float* __restrict__ bn2g, const float* __restrict__ bn2b,
                        const float* __restrict__ fc3W, const float* __restrict__ fc3b,
                        float* __restrict__ out) {
    __shared__ float z2s[2][DD3];
    int t = threadIdx.x;                 // 128
    {
        float a0 = f2acc[t] + fc2b[t];
        float a1 = f2acc[DD3 + t] + fc2b[t];
        float m = 0.5f * (a0 + a1);
        float d0 = a0 - m, d1 = a1 - m;
        float v = 0.5f * (d0 * d0 + d1 * d1);
        float is = 1.f / sqrtf(v + 1e-5f);
        float gj = bn2g[t], bj = bn2b[t];
        z2s[0][t] = fmaxf(d0 * is * gj + bj, 0.f);
        z2s[1][t] = fmaxf(d1 * is * gj + bj, 0.f);
    }
    __syncthreads();
    if (t < 4) {
        int g = t >> 1, c = t & 1;
        float acc = fc3b[c];
        for (int i = 0; i < DD3; ++i) acc += z2s[g][i] * fc3W[i * 2 + c];
        out[g * 2 + c] = acc;
    }
}

extern "C" void kernel_launch(void* const* d_in, const int* in_sizes, int n_in,
                              void* d_out, int out_size, void* d_ws, size_t ws_size,
                              hipStream_t stream) {
    (void)in_sizes; (void)n_in; (void)out_size; (void)ws_size;
    const float* x     = (const float*)d_in[0];
    const int*   eidx  = (const int*)d_in[1];
    const float* eattr = (const float*)d_in[3];
    const float* c1W1  = (const float*)d_in[6];
    const float* c1W2  = (const float*)d_in[7];
    const float* c1nb  = (const float*)d_in[8];
    const float* c1b   = (const float*)d_in[9];
    const float* p1w   = (const float*)d_in[10];
    const float* c2W1  = (const float*)d_in[11];
    const float* c2W2  = (const float*)d_in[12];
    const float* c2nb  = (const float*)d_in[13];
    const float* c2b   = (const float*)d_in[14];
    const float* p2w   = (const float*)d_in[15];
    const float* fc1W  = (const float*)d_in[16];
    const float* fc1b  = (const float*)d_in[17];
    const float* bn1g  = (const float*)d_in[18];
    const float* bn1b  = (const float*)d_in[19];
    const float* fc2W  = (const float*)d_in[20];
    const float* fc2b  = (const float*)d_in[21];
    const float* bn2g  = (const float*)d_in[22];
    const float* bn2b  = (const float*)d_in[23];
    const float* fc3W  = (const float*)d_in[24];
    const float* fc3b  = (const float*)d_in[25];

    const int* src = eidx;
    const int* dst = eidx + EE;

    char* w = (char*)d_ws;
    auto alloc = [&](size_t bytes) { void* p = (void*)w; w += ((bytes + 255) / 256) * 256; return p; };
    float* Abuf    = (float*)alloc((size_t)NN * KTOT * 4);
    int*   cnt1    = (int*)alloc(NN * 4);
    int*   bucket1 = (int*)alloc((size_t)NN * MAXIN * 4);
    float* xt1     = (float*)alloc((size_t)NN * DIM * 4);
    float* out1    = (float*)alloc((size_t)NN * DIM * 4);
    float* score1  = (float*)alloc(NN * 4);
    int*   perm1   = (int*)alloc(GG * KP1 * 4);
    int*   newidx1 = (int*)alloc(NN * 4);
    float* x1p     = (float*)alloc((size_t)GG * KP1 * DIM * 4);
    float* zbuf    = (float*)alloc(GG * 1328 * 4);
    int*   cnt2    = (int*)alloc(GG * KP1 * 4);
    int*   bucket2 = (int*)alloc((size_t)GG * KP1 * MAXIN * 4);
    float* xt2     = (float*)alloc((size_t)GG * KP1 * DIM * 4);
    float* out2    = (float*)alloc((size_t)GG * KP1 * DIM * 4);
    float* score2  = (float*)alloc(GG * KP1 * 4);
    int*   perm2   = (int*)alloc(GG * KP2 * 4);
    int*   newidx2 = (int*)alloc(GG * KP1 * 4);
    float* hacc    = (float*)alloc(2 * DIM * 4);
    float* f2acc   = (float*)alloc(2 * DD3 * 4);

    // ---- conv1 ----
    k_afull1<<<NN, 256, 0, stream>>>(x, c1W1, Abuf, xt1, cnt1);
    k_bucket<<<(EE + 255) / 256, 256, 0, stream>>>(dst, cnt1, bucket1);
    k_gemm<<<dim3((DIM + BN - 1) / BN, (NN + BM - 1) / BM, SPLITK), 256, 0, stream>>>(
        Abuf, c1W2, c1nb, xt1, NN);
    k_agg<<<NN, 256, 0, stream>>>(xt1, cnt1, bucket1, src, eattr, nullptr, c1b, out1);

    // ---- pool1 ----
    k_score<<<NN, 64, 0, stream>>>(out1, p1w, score1);
    k_topk<<<GG, 384, 0, stream>>>(score1, NPG, KP1, perm1, newidx1,
                                   cnt2, GG * KP1, nullptr, 0, nullptr, 0);
    k_gather<<<dim3(2, GG), 256, 0, stream>>>(out1, score1, perm1, KP1, x1p, zbuf, 0);
    k_bucketB<<<(EE + 255) / 256, 256, 0, stream>>>(src, dst, newidx1, cnt2, bucket2);

    // ---- conv2 ----
    k_afull2<<<GG * KP1, 256, 0, stream>>>(x1p, c2W1, perm1, Abuf, xt2);
    k_gemm<<<dim3((DIM + BN - 1) / BN, (GG * KP1 + BM - 1) / BM, SPLITK), 256, 0, stream>>>(
        Abuf, c2W2, c2nb, xt2, GG * KP1);
    k_agg<<<GG * KP1, 256, 0, stream>>>(xt2, cnt2, bucket2, src, eattr, newidx1, c2b, out2);

    // ---- pool2 ----
    k_score<<<GG * KP1, 64, 0, stream>>>(out2, p2w, score2);
    k_topk<<<GG, 384, 0, stream>>>(score2, KP1, KP2, perm2, newidx2,
                                   nullptr, 0, hacc, 2 * DIM, f2acc, 2 * DD3);
    k_gather<<<dim3(2, GG), 256, 0, stream>>>(out2, score2, perm2, KP2, nullptr, zbuf, 664);

    // ---- head ----
    k_fc1<<<dim3(3, 8), 128, 0, stream>>>(zbuf, fc1W, hacc);
    k_fc2<<<4, 128, 0, stream>>>(hacc, fc1b, bn1g, bn1b, fc2W, f2acc);
    k_head3<<<1, 128, 0, stream>>>(f2acc, fc2b, bn2g, bn2b, fc3W, fc3b, (float*)d_out);
}